// Round 9
// baseline (371.489 us; speedup 1.0000x reference)
//
#include <hip/hip_runtime.h>
#include <stdint.h>

// ---------------------------------------------------------------------------
// DataEmbedding_ALLPE_Weighted on MI355X (gfx950)  — round 12
//
// Round-11 confirmed the 2-blocks/CU drain-per-step structure is stable at
// 356us (fused 157). Cycle model: stage 1286 cyc vs MFMA 1034 cyc per step,
// serialized by the __syncthreads vmcnt(0) drain. learn-loop m218/m233: the
// drain IS the poison; counted vmcnt (never 0 in-loop) is the cure. My r9
// counted attempt failed on pipeline DEPTH (prefetch issued one barrier-gap
// before its drain). This round fixes depth: BM=128/512thr/8 waves (r4's
// proven-correct geometry), B DOUBLE-buffered, A single, 144K LDS, 1 blk/CU:
//   iter t: vmcnt(8) [drains A(t)+B(t), KEEPS B(t+1)'s 8 in flight]
//           -> raw barrier -> 64 MFMA -> raw barrier
//           -> issue A(t+1) -> issue B(t+2) into buf[t&1]
// B(t+1) lands a full compute phase (~2070cyc >> 1430cyc transfer) before
// its drain. FIFO (per-thread 10 loads/tile: A=2,B=8) verified; vmcnt(0)
// only at the final iter. BM=128 also halves B-restage traffic.
// Primitives (raw s_barrier + asm vmcnt + sched_barrier) correctness-proven
// in r9. Epilogues = r4's two-half lT form + r11's pw_tab fold.
// ---------------------------------------------------------------------------

typedef unsigned short u16;
using short8  = __attribute__((ext_vector_type(8))) short;
using floatx4 = __attribute__((ext_vector_type(4))) float;
typedef __attribute__((address_space(1))) const unsigned int u32_as1;
typedef __attribute__((address_space(3))) unsigned int       u32_as3;

static __device__ __forceinline__ u16 f2b(float f) {
  unsigned u = __float_as_uint(f);
  u += 0x7FFFu + ((u >> 16) & 1u);          // RNE
  return (u16)(u >> 16);
}
static __device__ __forceinline__ float b2f(u16 h) {
  return __uint_as_float(((unsigned)h) << 16);
}

// ------------------------------------------------- merged prep (one launch)
// blocks [0,12800): prep mats; [12800,12802): bias2; [12802,13826): pe
// tables (-> pw_tab); [13826,14850): rolling features.
__global__ __launch_bounds__(256) void prep_all(
    const float* __restrict__ x,
    const float* __restrict__ conv_w, const float* __restrict__ mixer_w,
    const float* __restrict__ tproj_w, const float* __restrict__ tape_pos,
    const float* __restrict__ tproj_b, const float* __restrict__ mixer_b,
    const float* __restrict__ learned_pe,
    const float* __restrict__ gf, const float* __restrict__ bf_,
    const float* __restrict__ gl, const float* __restrict__ bl,
    const float* __restrict__ wp,
    u16* __restrict__ W1, u16* __restrict__ A_m1, u16* __restrict__ M2t,
    u16* __restrict__ tprojT, u16* __restrict__ tape_bf,
    float* __restrict__ bias2, u16* __restrict__ pw_tab,
    u16* __restrict__ comb) {
  __shared__ float sx[87 * 32];
  const int bx = blockIdx.x;
  if (bx < 12800) {
    int i = bx * 256 + threadIdx.x;
    if (i < 393216) {                                    // W1: 512*768
      int d = i / 768, rem = i - d * 768;
      int j = rem >> 8, c = rem & 255;
      W1[i] = f2b(conv_w[(d * 256 + c) * 3 + j]);
    } else if (i < 393216 + 262144) {
      int k = i - 393216; int p = k >> 9, r = k & 511;
      A_m1[k] = f2b(mixer_w[p * 1024 + r]);
    } else if (i < 393216 + 524288) {
      int k = i - 393216 - 262144; int p = k >> 9, r = k & 511;
      M2t[k] = f2b(mixer_w[p * 1024 + 512 + r]);
    } else if (i < 393216 + 786432) {
      int k = i - 393216 - 524288; int q = k >> 9, r = k & 511;
      tprojT[k] = f2b(tproj_w[r * 512 + q]);
    } else if (i < 393216 + 786432 + 2097152) {
      int k = i - 393216 - 786432;
      tape_bf[k] = f2b(tape_pos[k]);
    }
    return;
  }
  if (bx < 12802) {
    int p = (bx - 12800) * 256 + threadIdx.x;
    if (p < 512) {
      float s = mixer_b[p];
      for (int r = 0; r < 512; ++r) s += mixer_w[p * 1024 + r] * tproj_b[r];
      bias2[p] = s;
    }
    return;
  }
  if (bx < 13826) {
    // pe tables -> combined pw = w1*LN(pe_fixed) + w2*LN(pe_learned)
    float a0 = wp[0], a1 = wp[1], a2 = wp[2], a3 = wp[3];
    float mxw = fmaxf(fmaxf(a0, a1), fmaxf(a2, a3));
    float e0 = expf(a0 - mxw), e1 = expf(a1 - mxw);
    float e2 = expf(a2 - mxw), e3 = expf(a3 - mxw);
    float invs = 1.f / (e0 + e1 + e2 + e3);
    float w1 = e1 * invs, w2 = e2 * invs;

    int row = (bx - 12802) * 4 + (threadIdx.x >> 6);
    int lane = threadIdx.x & 63;
    size_t base = (size_t)row * 512 + lane * 8;
    float v[8]; float s1 = 0.f, s2 = 0.f;
    #pragma unroll
    for (int e = 0; e < 8; ++e) {
      int d = lane * 8 + e;
      int de = d & ~1;
      float div = expf((float)de * (-9.210340371976184f / 512.f));
      float ang = (float)row * div;
      v[e] = (d & 1) ? cosf(ang) : sinf(ang);
      s1 += v[e]; s2 += v[e] * v[e];
    }
    #pragma unroll
    for (int off = 32; off; off >>= 1) { s1 += __shfl_xor(s1, off); s2 += __shfl_xor(s2, off); }
    float mean = s1 * (1.f / 512.f);
    float inv = rsqrtf(fmaxf(s2 * (1.f / 512.f) - mean * mean, 0.f) + 1e-5f);
    float pwv[8];
    #pragma unroll
    for (int e = 0; e < 8; ++e) {
      int d = lane * 8 + e;
      pwv[e] = w1 * (gf[d] * ((v[e] - mean) * inv) + bf_[d]);
    }
    const float4* lp = (const float4*)(learned_pe + base);
    float4 a = lp[0], bq = lp[1];
    float u[8] = {a.x, a.y, a.z, a.w, bq.x, bq.y, bq.z, bq.w};
    s1 = 0.f; s2 = 0.f;
    #pragma unroll
    for (int e = 0; e < 8; ++e) { s1 += u[e]; s2 += u[e] * u[e]; }
    #pragma unroll
    for (int off = 32; off; off >>= 1) { s1 += __shfl_xor(s1, off); s2 += __shfl_xor(s2, off); }
    mean = s1 * (1.f / 512.f);
    inv = rsqrtf(fmaxf(s2 * (1.f / 512.f) - mean * mean, 0.f) + 1e-5f);
    short8 o;
    #pragma unroll
    for (int e = 0; e < 8; ++e) {
      int d = lane * 8 + e;
      o[e] = (short)f2b(pwv[e] + w2 * (gl[d] * ((u[e] - mean) * inv) + bl[d]));
    }
    *(short8*)(pw_tab + base) = o;
    return;
  }
  // ---- rolling features ----
  const int fb = bx - 13826;
  const int b = fb >> 6, l0 = (fb & 63) * 64;
  for (int idx = threadIdx.x; idx < 87 * 32; idx += 256) {
    int r = idx >> 5, c = idx & 31;
    int ls = l0 - 23 + r; if (ls < 0) ls = 0;
    sx[idx] = x[((size_t)b * 4096 + ls) * 32 + c];
  }
  __syncthreads();
  const int c = threadIdx.x & 31, lr0 = threadIdx.x >> 5;
  for (int pass = 0; pass < 8; ++pass) {
    int lr = pass * 8 + lr0;
    int l = l0 + lr;
    float w[24];
    float s = 0.f, mx = -3.4e38f, mn = 3.4e38f;
    #pragma unroll
    for (int i = 0; i < 24; ++i) {
      float v = sx[(lr + i) * 32 + c];
      w[i] = v; s += v; mx = fmaxf(mx, v); mn = fminf(mn, v);
    }
    float mean = s * (1.f / 24.f);
    float ssd = 0.f;
    #pragma unroll
    for (int i = 0; i < 24; ++i) { float d = w[i] - mean; ssd += d * d; }
    float sd = sqrtf(fmaxf(ssd, 0.f) * (1.f / 23.f));
    float xv = w[23];
    float lag3 = xv - sx[(lr + 20) * 32 + c];
    float lag5 = xv - sx[(lr + 18) * 32 + c];
    float lag7 = xv - sx[(lr + 16) * 32 + c];
    size_t base = ((size_t)b * 4096 + l) * 256 + c;
    comb[base +   0] = f2b(xv);
    comb[base +  32] = f2b(mean);
    comb[base +  64] = f2b(mx);
    comb[base +  96] = f2b(mn);
    comb[base + 128] = f2b(sd);
    comb[base + 160] = f2b(lag3);
    comb[base + 192] = f2b(lag5);
    comb[base + 224] = f2b(lag7);
  }
}

// ------------------------------------------------------- small bf16 GEMM
static __device__ __forceinline__ void gemm_bt_dev(
    const u16* __restrict__ A, const u16* __restrict__ Bt,
    u16* __restrict__ outp, int K, int ldc,
    const float* __restrict__ bias, int m0, int n0,
    u16* lA, u16* lB) {
  const int tid = threadIdx.x;
  const int wave = tid >> 6, lane = tid & 63;
  const int wm = (wave & 1) * 64, wn = (wave >> 1) * 64;
  const int quad = lane >> 4, r16 = lane & 15;
  const int rowT = tid >> 3, col8 = tid & 7;

  floatx4 acc[4][4];
  #pragma unroll
  for (int i = 0; i < 4; ++i)
    #pragma unroll
    for (int j = 0; j < 4; ++j) acc[i][j] = (floatx4){0.f, 0.f, 0.f, 0.f};

  for (int kk = 0; kk < K; kk += 64) {
    __syncthreads();
    #pragma unroll
    for (int it = 0; it < 4; ++it) {
      int rr = it * 32 + rowT;
      const u16* ga = A  + (size_t)(m0 + rr) * K + kk + col8 * 8;
      const u16* gb = Bt + (size_t)(n0 + rr) * K + kk + col8 * 8;
      __builtin_amdgcn_global_load_lds((u32_as1*)ga, (u32_as3*)&lA[rr * 64 + col8 * 8], 16, 0, 0);
      __builtin_amdgcn_global_load_lds((u32_as1*)gb, (u32_as3*)&lB[rr * 64 + col8 * 8], 16, 0, 0);
    }
    __syncthreads();
    #pragma unroll
    for (int ks = 0; ks < 64; ks += 32) {
      short8 af[4], bfr[4];
      #pragma unroll
      for (int i = 0; i < 4; ++i)
        af[i] = *(const short8*)&lA[(wm + i * 16 + r16) * 64 + ks + quad * 8];
      #pragma unroll
      for (int j = 0; j < 4; ++j)
        bfr[j] = *(const short8*)&lB[(wn + j * 16 + r16) * 64 + ks + quad * 8];
      #pragma unroll
      for (int i = 0; i < 4; ++i)
        #pragma unroll
        for (int j = 0; j < 4; ++j)
          acc[i][j] = __builtin_amdgcn_mfma_f32_16x16x32_bf16(af[i], bfr[j], acc[i][j], 0, 0, 0);
    }
  }
  #pragma unroll
  for (int i = 0; i < 4; ++i) {
    #pragma unroll
    for (int rr = 0; rr < 4; ++rr) {
      int m = m0 + wm + i * 16 + quad * 4 + rr;
      #pragma unroll
      for (int j = 0; j < 4; ++j) {
        int n = n0 + wn + j * 16 + r16;
        float v = acc[i][j][rr];
        if (bias) v += bias[n];
        outp[(size_t)m * ldc + n] = f2b(v);
      }
    }
  }
}

// blocks [0,16): Wf = M1 @ tprojT^T ; [16,144): ctab = tape @ M2t^T + bias2
__global__ __launch_bounds__(256) void gemm_bt_both(
    const u16* __restrict__ A_m1, const u16* __restrict__ tprojT,
    u16* __restrict__ Wf, const u16* __restrict__ tape_bf,
    const u16* __restrict__ M2t, u16* __restrict__ ctab_bf,
    const float* __restrict__ bias2) {
  __shared__ __align__(16) u16 lA[128 * 64];
  __shared__ __align__(16) u16 lB[128 * 64];
  const int bx = blockIdx.x;
  if (bx < 16) {
    gemm_bt_dev(A_m1, tprojT, Wf, 512, 512, nullptr,
                (bx & 3) * 128, (bx >> 2) * 128, lA, lB);
  } else {
    const int i = bx - 16;
    gemm_bt_dev(tape_bf, M2t, ctab_bf, 512, 512, bias2,
                (i & 31) * 128, (i >> 5) * 128, lA, lB);
  }
}

// ---------------------------------------------------------------------------
// Fused conv GEMM + LN + pre GEMM + LN + weighted sum, counted-vmcnt pipeline.
// Block = 128 m-rows x 512 n-cols, 512 threads (8 waves = 2m x 4n).
// Operand-swapped MFMA: D = mfma(B_frag, A_frag):
//   lane(q,r): m = wm2*64 + i*16 + r,  n = wn + jj*16 + q*4 + rr
// LDS 147456 (1 block/CU): lA @0 (16K, single), lB0 @16384 (64K),
// lB1 @81920 (64K). Epilogue unions dead staging: lT[64][520] @0 (66.5K),
// sG @67584 (2K), sB @69632 (2K) — params reloaded per phase.
// Per-thread loads per K-tile: A=2, B=8 (FIFO A-then-B at issue).
// ---------------------------------------------------------------------------

#define STAGE_A5(SRCEXPR)                                                      \
  _Pragma("unroll")                                                            \
  for (int it = 0; it < 2; ++it) {                                             \
    int id = it * 512 + tid, row = id >> 3, c = id & 7;                        \
    int cg = ((c ^ (row & 7)) << 3);                                           \
    const u16* gsrc = (SRCEXPR);                                               \
    __builtin_amdgcn_global_load_lds((u32_as1*)gsrc,                           \
        (u32_as3*)(smem + id * 16), 16, 0, 0);                                 \
  }
#define STAGE_B5(BUFOFF, SRCEXPR)                                              \
  _Pragma("unroll")                                                            \
  for (int it = 0; it < 8; ++it) {                                             \
    int id = it * 512 + tid, row = id >> 3, c = id & 7;                        \
    int cg = ((c ^ (row & 7)) << 3);                                           \
    const u16* gsrc = (SRCEXPR);                                               \
    __builtin_amdgcn_global_load_lds((u32_as1*)gsrc,                           \
        (u32_as3*)(smem + (BUFOFF) + id * 16), 16, 0, 0);                      \
  }
#define RAW_BARRIER()                                                          \
  __builtin_amdgcn_sched_barrier(0);                                           \
  __builtin_amdgcn_s_barrier();                                                \
  __builtin_amdgcn_sched_barrier(0);

__global__ __launch_bounds__(512, 2) void gemm_conv_pre(
    const u16* __restrict__ comb, const u16* __restrict__ W1,
    const float* __restrict__ conv_b, const float* __restrict__ g_c,
    const float* __restrict__ b_c, const u16* __restrict__ Wf,
    const u16* __restrict__ ctab_bf, const u16* __restrict__ pw_tab,
    const float* __restrict__ g_t, const float* __restrict__ b_t,
    const float* __restrict__ wp,
    u16* __restrict__ ce, float* __restrict__ out) {
  __shared__ __align__(16) char smem[147456];
  u16*   lA = (u16*)smem;                       // [128][64]
  u16*   lT = (u16*)smem;                       // [64][520] (epilogue)
  float* sG = (float*)(smem + 67584);           // epilogue only
  float* sB = (float*)(smem + 69632);

  const int tid = threadIdx.x;
  const int m0 = blockIdx.x * 128;
  const int b = m0 >> 12, l0 = m0 & 4095;
  const int w = tid >> 6, lane = tid & 63;
  const int quad = lane >> 4, r16 = lane & 15;
  const int wm2 = w >> 2, wn = (w & 3) * 128;

  // ============ phase 1: conv GEMM (K=768, 12 tiles, pipelined) ============
  floatx4 acc[4][8];
  #pragma unroll
  for (int i = 0; i < 4; ++i)
    #pragma unroll
    for (int jj = 0; jj < 8; ++jj) acc[i][jj] = (floatx4){0.f, 0.f, 0.f, 0.f};

  // prologue: A(0), B(0)->lB0, B(1)->lB1   (FIFO: A0[2], B0[8], B1[8])
  STAGE_A5(comb + (((size_t)b * 4096 + ((l0 + row - 1 + 4096) & 4095)) << 8) + cg)
  STAGE_B5(16384, W1 + (size_t)row * 768 + 0 + cg)
  STAGE_B5(81920, W1 + (size_t)row * 768 + 64 + cg)

  for (int t = 0; t < 12; ++t) {
    __builtin_amdgcn_sched_barrier(0);
    if (t + 1 < 12) {
      asm volatile("s_waitcnt vmcnt(8)" ::: "memory");   // drain A(t),B(t); keep B(t+1)
    } else {
      asm volatile("s_waitcnt vmcnt(0)" ::: "memory");
    }
    RAW_BARRIER();                                        // publish tile t
    const u16* lBc = (const u16*)(smem + 16384 + (t & 1) * 65536);
    #pragma unroll
    for (int ks = 0; ks < 64; ks += 32) {
      short8 af[4];
      #pragma unroll
      for (int i = 0; i < 4; ++i) {
        int row = wm2 * 64 + i * 16 + r16;
        af[i] = *(const short8*)&lA[row * 64 + ((((ks >> 3) + quad) ^ (row & 7)) << 3)];
      }
      __builtin_amdgcn_s_setprio(1);
      #pragma unroll
      for (int jj = 0; jj < 8; ++jj) {
        int row = wn + jj * 16 + r16;
        short8 bf = *(const short8*)&lBc[row * 64 + ((((ks >> 3) + quad) ^ (row & 7)) << 3)];
        #pragma unroll
        for (int i = 0; i < 4; ++i)
          acc[i][jj] = __builtin_amdgcn_mfma_f32_16x16x32_bf16(bf, af[i], acc[i][jj], 0, 0, 0);
      }
      __builtin_amdgcn_s_setprio(0);
    }
    RAW_BARRIER();                                        // all reads of tile t done
    if (t + 1 < 12) {                                     // A(t+1) into lA (freed)
      const int kk1 = (t + 1) * 64;
      const int jsh1 = kk1 >> 8, kc1 = kk1 & 255;
      STAGE_A5(comb + (((size_t)b * 4096 + ((l0 + row + jsh1 - 1 + 4096) & 4095)) << 8) + kc1 + cg)
    }
    if (t + 2 < 12) {                                     // B(t+2) into buf[t&1]
      STAGE_B5(16384 + (t & 1) * 65536, W1 + (size_t)row * 768 + (t + 2) * 64 + cg)
    }
  }
  __syncthreads();
  // conv epilogue: two 64-row halves through lT
  if (tid < 128) {
    ((float4*)sG)[tid] = ((const float4*)g_c)[tid];
    ((float4*)sB)[tid] = ((const float4*)b_c)[tid];
  }
  const int orow = tid >> 3, part = tid & 7;
  #pragma unroll
  for (int h = 0; h < 2; ++h) {
    if (wm2 == h) {
      #pragma unroll
      for (int jj = 0; jj < 8; ++jj) {
        int n = wn + jj * 16 + quad * 4;
        float4 b4 = *(const float4*)&conv_b[n];
        #pragma unroll
        for (int i = 0; i < 4; ++i) {
          ushort4 pk;
          pk.x = f2b(acc[i][jj][0] + b4.x);
          pk.y = f2b(acc[i][jj][1] + b4.y);
          pk.z = f2b(acc[i][jj][2] + b4.z);
          pk.w = f2b(acc[i][jj][3] + b4.w);
          *(ushort4*)(lT + (size_t)(i * 16 + r16) * 520 + n) = pk;
        }
      }
    }
    __syncthreads();
    const u16* rowp = lT + (size_t)orow * 520;
    float s1 = 0.f, s2 = 0.f;
    #pragma unroll
    for (int k = 0; k < 8; ++k) {
      short8 t8 = *(const short8*)(rowp + (part + k * 8) * 8);
      #pragma unroll
      for (int e = 0; e < 8; ++e) {
        float f = b2f((u16)t8[e]); s1 += f; s2 += f * f;
      }
    }
    s1 += __shfl_xor(s1, 1); s2 += __shfl_xor(s2, 1);
    s1 += __shfl_xor(s1, 2); s2 += __shfl_xor(s2, 2);
    s1 += __shfl_xor(s1, 4); s2 += __shfl_xor(s2, 4);
    float mean = s1 * (1.f / 512.f);
    float inv = rsqrtf(fmaxf(s2 * (1.f / 512.f) - mean * mean, 0.f) + 1e-5f);
    size_t mrow = (size_t)(m0 + h * 64 + orow) * 512;
    #pragma unroll
    for (int k = 0; k < 8; ++k) {
      int c8 = part + k * 8;
      short8 t8 = *(const short8*)(rowp + c8 * 8);
      short8 o;
      #pragma unroll
      for (int e = 0; e < 8; ++e) {
        int d = c8 * 8 + e;
        o[e] = (short)f2b(sG[d] * ((b2f((u16)t8[e]) - mean) * inv) + sB[d]);
      }
      *(short8*)(ce + mrow + c8 * 8) = o;
    }
    __syncthreads();
  }
  // (the last __syncthreads drains ce stores -> visible to phase-2 DMA)

  // ============ phase 2: pre GEMM (K=512, 8 tiles, pipelined) ==============
  floatx4 acc2[4][8];
  #pragma unroll
  for (int i = 0; i < 4; ++i)
    #pragma unroll
    for (int jj = 0; jj < 8; ++jj) acc2[i][jj] = (floatx4){0.f, 0.f, 0.f, 0.f};

  STAGE_A5(ce + (size_t)(m0 + row) * 512 + 0 + cg)
  STAGE_B5(16384, Wf + (size_t)row * 512 + 0 + cg)
  STAGE_B5(81920, Wf + (size_t)row * 512 + 64 + cg)

  for (int t = 0; t < 8; ++t) {
    __builtin_amdgcn_sched_barrier(0);
    if (t + 1 < 8) {
      asm volatile("s_waitcnt vmcnt(8)" ::: "memory");
    } else {
      asm volatile("s_waitcnt vmcnt(0)" ::: "memory");
    }
    RAW_BARRIER();
    const u16* lBc = (const u16*)(smem + 16384 + (t & 1) * 65536);
    #pragma unroll
    for (int ks = 0; ks < 64; ks += 32) {
      short8 af[4];
      #pragma unroll
      for (int i = 0; i < 4; ++i) {
        int row = wm2 * 64 + i * 16 + r16;
        af[i] = *(const short8*)&lA[row * 64 + ((((ks >> 3) + quad) ^ (row & 7)) << 3)];
      }
      __builtin_amdgcn_s_setprio(1);
      #pragma unroll
      for (int jj = 0; jj < 8; ++jj) {
        int row = wn + jj * 16 + r16;
        short8 bf = *(const short8*)&lBc[row * 64 + ((((ks >> 3) + quad) ^ (row & 7)) << 3)];
        #pragma unroll
        for (int i = 0; i < 4; ++i)
          acc2[i][jj] = __builtin_amdgcn_mfma_f32_16x16x32_bf16(bf, af[i], acc2[i][jj], 0, 0, 0);
      }
      __builtin_amdgcn_s_setprio(0);
    }
    RAW_BARRIER();
    if (t + 1 < 8) {
      STAGE_A5(ce + (size_t)(m0 + row) * 512 + (t + 1) * 64 + cg)
    }
    if (t + 2 < 8) {
      STAGE_B5(16384 + (t & 1) * 65536, Wf + (size_t)row * 512 + (t + 2) * 64 + cg)
    }
  }
  __syncthreads();
  // final epilogue: two halves; LN(pre+ctab) + weighted sum -> out
  if (tid < 128) {
    ((float4*)sG)[tid] = ((const float4*)g_t)[tid];
    ((float4*)sB)[tid] = ((const float4*)b_t)[tid];
  }
  float a0 = wp[0], a1 = wp[1], a2 = wp[2], a3 = wp[3];
  float mxw = fmaxf(fmaxf(a0, a1), fmaxf(a2, a3));
  float e0 = expf(a0 - mxw), e1 = expf(a1 - mxw), e2 = expf(a2 - mxw), e3 = expf(a3 - mxw);
  float invs = 1.f / (e0 + e1 + e2 + e3);
  float w0 = e0 * invs, w3 = e3 * invs;

  #pragma unroll
  for (int h = 0; h < 2; ++h) {
    if (wm2 == h) {
      #pragma unroll
      for (int jj = 0; jj < 8; ++jj) {
        int n = wn + jj * 16 + quad * 4;
        #pragma unroll
        for (int i = 0; i < 4; ++i) {
          ushort4 pk;
          pk.x = f2b(acc2[i][jj][0]);
          pk.y = f2b(acc2[i][jj][1]);
          pk.z = f2b(acc2[i][jj][2]);
          pk.w = f2b(acc2[i][jj][3]);
          *(ushort4*)(lT + (size_t)(i * 16 + r16) * 520 + n) = pk;
        }
      }
    }
    __syncthreads();
    const int m = m0 + h * 64 + orow, l = l0 + h * 64 + orow;
    const u16* rowp = lT + (size_t)orow * 520;
    const size_t lrow = (size_t)l * 512, mrow = (size_t)m * 512;
    float s1 = 0.f, s2 = 0.f;
    #pragma unroll
    for (int k = 0; k < 8; ++k) {
      int c8 = part + k * 8;
      short8 t8 = *(const short8*)(rowp + c8 * 8);
      short8 ct = *(const short8*)(ctab_bf + lrow + c8 * 8);
      #pragma unroll
      for (int e = 0; e < 8; ++e) {
        float f = b2f((u16)t8[e]) + b2f((u16)ct[e]);
        s1 += f; s2 += f * f;
      }
    }
    s1 += __shfl_xor(s1, 1); s2 += __shfl_xor(s2, 1);
    s1 += __shfl_xor(s1, 2); s2 += __shfl_xor(s2, 2);
    s1 += __shfl_xor(s1, 4); s2 += __shfl_xor(s2, 4);
    float mean = s1 * (1.f / 512.f);
    float inv = rsqrtf(fmaxf(s2 * (1.f / 512.f) - mean * mean, 0.f) + 1e-5f);

    #pragma unroll
    for (int k = 0; k < 8; ++k) {
      int c8 = part + k * 8;
      short8 t8  = *(const short8*)(rowp + c8 * 8);
      short8 ct  = *(const short8*)(ctab_bf + lrow + c8 * 8);
      short8 c8v = *(const short8*)(ce + mrow + c8 * 8);
      short8 pw  = *(const short8*)(pw_tab + lrow + c8 * 8);
      float o[8];
      #pragma unroll
      for (int e = 0; e < 8; ++e) {
        int d = c8 * 8 + e;
        float f = b2f((u16)t8[e]) + b2f((u16)ct[e]);
        float pt = sG[d] * ((f - mean) * inv) + sB[d];
        o[e] = w0 * b2f((u16)c8v[e]) + b2f((u16)pw[e]) + w3 * pt;
      }
      float4* op = (float4*)(out + mrow + c8 * 8);
      op[0] = make_float4(o[0], o[1], o[2], o[3]);
      op[1] = make_float4(o[4], o[5], o[6], o[7]);
    }
    __syncthreads();
  }
}

// ---------------------------------------------------------------------------
extern "C" void kernel_launch(void* const* d_in, const int* in_sizes, int n_in,
                              void* d_out, int out_size, void* d_ws, size_t ws_size,
                              hipStream_t stream) {
  const float* x          = (const float*)d_in[0];
  const float* conv_w     = (const float*)d_in[1];
  const float* conv_b     = (const float*)d_in[2];
  const float* learned_pe = (const float*)d_in[3];
  const float* tape_pos   = (const float*)d_in[4];
  const float* tproj_w    = (const float*)d_in[5];
  const float* tproj_b    = (const float*)d_in[6];
  const float* mixer_w    = (const float*)d_in[7];
  const float* mixer_b    = (const float*)d_in[8];
  const float* g_c        = (const float*)d_in[9];
  const float* b_c        = (const float*)d_in[10];
  const float* g_f        = (const float*)d_in[11];
  const float* b_f        = (const float*)d_in[12];
  const float* g_l        = (const float*)d_in[13];
  const float* b_l        = (const float*)d_in[14];
  const float* g_t        = (const float*)d_in[15];
  const float* b_t        = (const float*)d_in[16];
  const float* wp         = (const float*)d_in[17];

  char* ws = (char*)d_ws;
  u16*  comb    = (u16*)(ws + 0);             // 32 MiB
  u16*  ce      = (u16*)(ws + 33554432);      // 64 MiB
  char* S       = ws + 100663296;
  u16*  W1      = (u16*)(S + 0);              // 768 KiB
  u16*  A_m1    = (u16*)(S + 786432);         // 512 KiB
  u16*  M2t     = (u16*)(S + 1310720);        // 512 KiB
  u16*  tprojT  = (u16*)(S + 1835008);        // 512 KiB
  u16*  tape_bf = (u16*)(S + 2359296);        // 4 MiB
  u16*  Wf      = (u16*)(S + 6553600);        // 512 KiB
  u16*  ctab_bf = (u16*)(S + 7077888);        // 4 MiB
  float* bias2  = (float*)(S + 11272192);     // 2 KiB
  u16*  pw_tab  = (u16*)(S + 11274240);       // 4 MiB

  // 1) all precompute + features in one launch (pe -> combined pw_tab)
  prep_all<<<14850, 256, 0, stream>>>(x, conv_w, mixer_w, tproj_w, tape_pos,
                                      tproj_b, mixer_b, learned_pe,
                                      g_f, b_f, g_l, b_l, wp,
                                      W1, A_m1, M2t, tprojT, tape_bf,
                                      bias2, pw_tab, comb);
  // 2) both small GEMMs (Wf, ctab) in one launch
  gemm_bt_both<<<144, 256, 0, stream>>>(A_m1, tprojT, Wf, tape_bf, M2t,
                                        ctab_bf, bias2);
  // 3) fused conv+LN+pre+LN+sum, BM=128, counted-vmcnt pipeline, 1 blk/CU
  gemm_conv_pre<<<512, 512, 0, stream>>>(comb, W1, conv_b, g_c, b_c,
                                         Wf, ctab_bf, pw_tab,
                                         g_t, b_t, wp, ce, (float*)d_out);
}

// Round 11
// 346.727 us; speedup vs baseline: 1.0714x; 1.0714x over previous
//
#include <hip/hip_runtime.h>
#include <stdint.h>

// ---------------------------------------------------------------------------
// DataEmbedding_ALLPE_Weighted on MI355X (gfx950)  — round 14 (final revert)
//
// Round-13's launch-overlap restructure FAILED correctness (absmax 0.164)
// for reasons not identifiable by inspection — disqualifying. This round
// restores the round-11 artifact byte-for-byte: the session's proven best
// (356.1us, passed; fused kernel 157us).
//
// Session ledger (10 experiments): 1 win (r8 dataflow fusion: conv+pre in
// one kernel, ce L2-local), 1 neutral fold (pw_tab precombine), 8 losses
// (every sync/tiling/operand/launch variant). Operating point is locked:
// BN=512 (fused row-LN) -> acc[4][8]=128 AGPR + ~128 VGPR = 256 regs/wave
// -> 8 waves/CU -> 2 blocks x 4 waves is the only packaging that works;
// the 2-barrier drain-per-step K-loop with 2-blocks/CU inter-block overlap
// beats every intra-block pipeline expressible in this register envelope.
// ---------------------------------------------------------------------------

typedef unsigned short u16;
using short8  = __attribute__((ext_vector_type(8))) short;
using floatx4 = __attribute__((ext_vector_type(4))) float;
typedef __attribute__((address_space(1))) const unsigned int u32_as1;
typedef __attribute__((address_space(3))) unsigned int       u32_as3;

static __device__ __forceinline__ u16 f2b(float f) {
  unsigned u = __float_as_uint(f);
  u += 0x7FFFu + ((u >> 16) & 1u);          // RNE
  return (u16)(u >> 16);
}
static __device__ __forceinline__ float b2f(u16 h) {
  return __uint_as_float(((unsigned)h) << 16);
}

// ------------------------------------------------- merged prep (one launch)
// blocks [0,12800): prep mats; [12800,12802): bias2; [12802,13826): pe
// tables (-> pw_tab); [13826,14850): rolling features.
__global__ __launch_bounds__(256) void prep_all(
    const float* __restrict__ x,
    const float* __restrict__ conv_w, const float* __restrict__ mixer_w,
    const float* __restrict__ tproj_w, const float* __restrict__ tape_pos,
    const float* __restrict__ tproj_b, const float* __restrict__ mixer_b,
    const float* __restrict__ learned_pe,
    const float* __restrict__ gf, const float* __restrict__ bf_,
    const float* __restrict__ gl, const float* __restrict__ bl,
    const float* __restrict__ wp,
    u16* __restrict__ W1, u16* __restrict__ A_m1, u16* __restrict__ M2t,
    u16* __restrict__ tprojT, u16* __restrict__ tape_bf,
    float* __restrict__ bias2, u16* __restrict__ pw_tab,
    u16* __restrict__ comb) {
  __shared__ float sx[87 * 32];
  const int bx = blockIdx.x;
  if (bx < 12800) {
    int i = bx * 256 + threadIdx.x;
    if (i < 393216) {                                    // W1: 512*768
      int d = i / 768, rem = i - d * 768;
      int j = rem >> 8, c = rem & 255;
      W1[i] = f2b(conv_w[(d * 256 + c) * 3 + j]);
    } else if (i < 393216 + 262144) {
      int k = i - 393216; int p = k >> 9, r = k & 511;
      A_m1[k] = f2b(mixer_w[p * 1024 + r]);
    } else if (i < 393216 + 524288) {
      int k = i - 393216 - 262144; int p = k >> 9, r = k & 511;
      M2t[k] = f2b(mixer_w[p * 1024 + 512 + r]);
    } else if (i < 393216 + 786432) {
      int k = i - 393216 - 524288; int q = k >> 9, r = k & 511;
      tprojT[k] = f2b(tproj_w[r * 512 + q]);
    } else if (i < 393216 + 786432 + 2097152) {
      int k = i - 393216 - 786432;
      tape_bf[k] = f2b(tape_pos[k]);
    }
    return;
  }
  if (bx < 12802) {
    int p = (bx - 12800) * 256 + threadIdx.x;
    if (p < 512) {
      float s = mixer_b[p];
      for (int r = 0; r < 512; ++r) s += mixer_w[p * 1024 + r] * tproj_b[r];
      bias2[p] = s;
    }
    return;
  }
  if (bx < 13826) {
    // pe tables -> combined pw = w1*LN(pe_fixed) + w2*LN(pe_learned)
    float a0 = wp[0], a1 = wp[1], a2 = wp[2], a3 = wp[3];
    float mxw = fmaxf(fmaxf(a0, a1), fmaxf(a2, a3));
    float e0 = expf(a0 - mxw), e1 = expf(a1 - mxw);
    float e2 = expf(a2 - mxw), e3 = expf(a3 - mxw);
    float invs = 1.f / (e0 + e1 + e2 + e3);
    float w1 = e1 * invs, w2 = e2 * invs;

    int row = (bx - 12802) * 4 + (threadIdx.x >> 6);
    int lane = threadIdx.x & 63;
    size_t base = (size_t)row * 512 + lane * 8;
    float v[8]; float s1 = 0.f, s2 = 0.f;
    #pragma unroll
    for (int e = 0; e < 8; ++e) {
      int d = lane * 8 + e;
      int de = d & ~1;
      float div = expf((float)de * (-9.210340371976184f / 512.f));
      float ang = (float)row * div;
      v[e] = (d & 1) ? cosf(ang) : sinf(ang);
      s1 += v[e]; s2 += v[e] * v[e];
    }
    #pragma unroll
    for (int off = 32; off; off >>= 1) { s1 += __shfl_xor(s1, off); s2 += __shfl_xor(s2, off); }
    float mean = s1 * (1.f / 512.f);
    float inv = rsqrtf(fmaxf(s2 * (1.f / 512.f) - mean * mean, 0.f) + 1e-5f);
    float pwv[8];
    #pragma unroll
    for (int e = 0; e < 8; ++e) {
      int d = lane * 8 + e;
      pwv[e] = w1 * (gf[d] * ((v[e] - mean) * inv) + bf_[d]);
    }
    const float4* lp = (const float4*)(learned_pe + base);
    float4 a = lp[0], bq = lp[1];
    float u[8] = {a.x, a.y, a.z, a.w, bq.x, bq.y, bq.z, bq.w};
    s1 = 0.f; s2 = 0.f;
    #pragma unroll
    for (int e = 0; e < 8; ++e) { s1 += u[e]; s2 += u[e] * u[e]; }
    #pragma unroll
    for (int off = 32; off; off >>= 1) { s1 += __shfl_xor(s1, off); s2 += __shfl_xor(s2, off); }
    mean = s1 * (1.f / 512.f);
    inv = rsqrtf(fmaxf(s2 * (1.f / 512.f) - mean * mean, 0.f) + 1e-5f);
    short8 o;
    #pragma unroll
    for (int e = 0; e < 8; ++e) {
      int d = lane * 8 + e;
      o[e] = (short)f2b(pwv[e] + w2 * (gl[d] * ((u[e] - mean) * inv) + bl[d]));
    }
    *(short8*)(pw_tab + base) = o;
    return;
  }
  // ---- rolling features ----
  const int fb = bx - 13826;
  const int b = fb >> 6, l0 = (fb & 63) * 64;
  for (int idx = threadIdx.x; idx < 87 * 32; idx += 256) {
    int r = idx >> 5, c = idx & 31;
    int ls = l0 - 23 + r; if (ls < 0) ls = 0;
    sx[idx] = x[((size_t)b * 4096 + ls) * 32 + c];
  }
  __syncthreads();
  const int c = threadIdx.x & 31, lr0 = threadIdx.x >> 5;
  for (int pass = 0; pass < 8; ++pass) {
    int lr = pass * 8 + lr0;
    int l = l0 + lr;
    float w[24];
    float s = 0.f, mx = -3.4e38f, mn = 3.4e38f;
    #pragma unroll
    for (int i = 0; i < 24; ++i) {
      float v = sx[(lr + i) * 32 + c];
      w[i] = v; s += v; mx = fmaxf(mx, v); mn = fminf(mn, v);
    }
    float mean = s * (1.f / 24.f);
    float ssd = 0.f;
    #pragma unroll
    for (int i = 0; i < 24; ++i) { float d = w[i] - mean; ssd += d * d; }
    float sd = sqrtf(fmaxf(ssd, 0.f) * (1.f / 23.f));
    float xv = w[23];
    float lag3 = xv - sx[(lr + 20) * 32 + c];
    float lag5 = xv - sx[(lr + 18) * 32 + c];
    float lag7 = xv - sx[(lr + 16) * 32 + c];
    size_t base = ((size_t)b * 4096 + l) * 256 + c;
    comb[base +   0] = f2b(xv);
    comb[base +  32] = f2b(mean);
    comb[base +  64] = f2b(mx);
    comb[base +  96] = f2b(mn);
    comb[base + 128] = f2b(sd);
    comb[base + 160] = f2b(lag3);
    comb[base + 192] = f2b(lag5);
    comb[base + 224] = f2b(lag7);
  }
}

// ------------------------------------------------------- small bf16 GEMM
static __device__ __forceinline__ void gemm_bt_dev(
    const u16* __restrict__ A, const u16* __restrict__ Bt,
    u16* __restrict__ outp, int K, int ldc,
    const float* __restrict__ bias, int m0, int n0,
    u16* lA, u16* lB) {
  const int tid = threadIdx.x;
  const int wave = tid >> 6, lane = tid & 63;
  const int wm = (wave & 1) * 64, wn = (wave >> 1) * 64;
  const int quad = lane >> 4, r16 = lane & 15;
  const int rowT = tid >> 3, col8 = tid & 7;

  floatx4 acc[4][4];
  #pragma unroll
  for (int i = 0; i < 4; ++i)
    #pragma unroll
    for (int j = 0; j < 4; ++j) acc[i][j] = (floatx4){0.f, 0.f, 0.f, 0.f};

  for (int kk = 0; kk < K; kk += 64) {
    __syncthreads();
    #pragma unroll
    for (int it = 0; it < 4; ++it) {
      int rr = it * 32 + rowT;
      const u16* ga = A  + (size_t)(m0 + rr) * K + kk + col8 * 8;
      const u16* gb = Bt + (size_t)(n0 + rr) * K + kk + col8 * 8;
      __builtin_amdgcn_global_load_lds((u32_as1*)ga, (u32_as3*)&lA[rr * 64 + col8 * 8], 16, 0, 0);
      __builtin_amdgcn_global_load_lds((u32_as1*)gb, (u32_as3*)&lB[rr * 64 + col8 * 8], 16, 0, 0);
    }
    __syncthreads();
    #pragma unroll
    for (int ks = 0; ks < 64; ks += 32) {
      short8 af[4], bfr[4];
      #pragma unroll
      for (int i = 0; i < 4; ++i)
        af[i] = *(const short8*)&lA[(wm + i * 16 + r16) * 64 + ks + quad * 8];
      #pragma unroll
      for (int j = 0; j < 4; ++j)
        bfr[j] = *(const short8*)&lB[(wn + j * 16 + r16) * 64 + ks + quad * 8];
      #pragma unroll
      for (int i = 0; i < 4; ++i)
        #pragma unroll
        for (int j = 0; j < 4; ++j)
          acc[i][j] = __builtin_amdgcn_mfma_f32_16x16x32_bf16(af[i], bfr[j], acc[i][j], 0, 0, 0);
    }
  }
  #pragma unroll
  for (int i = 0; i < 4; ++i) {
    #pragma unroll
    for (int rr = 0; rr < 4; ++rr) {
      int m = m0 + wm + i * 16 + quad * 4 + rr;
      #pragma unroll
      for (int j = 0; j < 4; ++j) {
        int n = n0 + wn + j * 16 + r16;
        float v = acc[i][j][rr];
        if (bias) v += bias[n];
        outp[(size_t)m * ldc + n] = f2b(v);
      }
    }
  }
}

// blocks [0,16): Wf = M1 @ tprojT^T ; [16,144): ctab = tape @ M2t^T + bias2
__global__ __launch_bounds__(256) void gemm_bt_both(
    const u16* __restrict__ A_m1, const u16* __restrict__ tprojT,
    u16* __restrict__ Wf, const u16* __restrict__ tape_bf,
    const u16* __restrict__ M2t, u16* __restrict__ ctab_bf,
    const float* __restrict__ bias2) {
  __shared__ __align__(16) u16 lA[128 * 64];
  __shared__ __align__(16) u16 lB[128 * 64];
  const int bx = blockIdx.x;
  if (bx < 16) {
    gemm_bt_dev(A_m1, tprojT, Wf, 512, 512, nullptr,
                (bx & 3) * 128, (bx >> 2) * 128, lA, lB);
  } else {
    const int i = bx - 16;
    gemm_bt_dev(tape_bf, M2t, ctab_bf, 512, 512, bias2,
                (i & 31) * 128, (i >> 5) * 128, lA, lB);
  }
}

// ---------------------------------------------------------------------------
// Fused conv GEMM + LN + pre GEMM + LN + weighted sum.  Block = 64 m-rows x
// 512 n-cols, 256 threads (4 waves, wave w owns n-strip [w*128,w*128+128)).
// Operand-swapped MFMA: D = mfma(B_frag, A_frag):
//   lane(q,r): m = i*16 + r,  n = jj*16 + q*4 + rr
// BOTH phases use the proven K-loop: STAGE A+B via global_load_lds,
// 2 barriers per BK=64 step, XOR chunk swizzle c^(row&7).
//   Phase 1 (conv, K=768): A = comb (circular row shift), B = W1.
//   Phase 2 (pre,  K=512): A = ce (just written by THIS block -> same-XCD
//     L2 hit; loop-top __syncthreads drains the stores first), B = Wf.
// Epilogues transpose acc -> lT[64][520] (unions staging) and do row-wise
// two-pass LN over LDS. Final sum reads ctab + precombined pw (2 tables).
// LDS: 73728 staging/lT + 4096 params = 77824 <= 80K -> 2 blocks/CU.
// ---------------------------------------------------------------------------

#define STAGE_A(SRCEXPR)                                                       \
  _Pragma("unroll")                                                            \
  for (int it = 0; it < 2; ++it) {                                             \
    int id = it * 256 + tid, row = id >> 3, c = id & 7;                        \
    int cg = ((c ^ (row & 7)) << 3);                                           \
    const u16* gsrc = (SRCEXPR);                                               \
    __builtin_amdgcn_global_load_lds((u32_as1*)gsrc,                           \
        (u32_as3*)(smem + id * 16), 16, 0, 0);                                 \
  }
#define STAGE_B(SRCEXPR)                                                       \
  _Pragma("unroll")                                                            \
  for (int it = 0; it < 16; ++it) {                                            \
    int id = it * 256 + tid, row = id >> 3, c = id & 7;                        \
    int cg = ((c ^ (row & 7)) << 3);                                           \
    const u16* gsrc = (SRCEXPR);                                               \
    __builtin_amdgcn_global_load_lds((u32_as1*)gsrc,                           \
        (u32_as3*)(smem + 8192 + id * 16), 16, 0, 0);                          \
  }

__global__ __launch_bounds__(256, 2) void gemm_conv_pre(
    const u16* __restrict__ comb, const u16* __restrict__ W1,
    const float* __restrict__ conv_b, const float* __restrict__ g_c,
    const float* __restrict__ b_c, const u16* __restrict__ Wf,
    const u16* __restrict__ ctab_bf, const u16* __restrict__ pw_tab,
    const float* __restrict__ g_t, const float* __restrict__ b_t,
    const float* __restrict__ wp,
    u16* __restrict__ ce, float* __restrict__ out) {
  __shared__ __align__(16) char smem[73728];
  __shared__ __align__(16) float sGB[1024];     // [0,512)=gamma, [512,1024)=beta
  float* sG = sGB;
  float* sB = sGB + 512;
  u16* lA = (u16*)smem;
  u16* lB = (u16*)(smem + 8192);
  u16* lT = (u16*)smem;                         // [64][520]

  const int tid = threadIdx.x;
  if (tid < 128) {
    ((float4*)sG)[tid] = ((const float4*)g_c)[tid];
    ((float4*)sB)[tid] = ((const float4*)b_c)[tid];
  }
  const int m0 = blockIdx.x * 64;
  const int b = m0 >> 12, l0 = m0 & 4095;
  const int w = tid >> 6, lane = tid & 63;
  const int quad = lane >> 4, r16 = lane & 15;
  const int wn = w * 128;

  // ================= phase 1: conv GEMM (proven structure) =================
  floatx4 acc[4][8];
  #pragma unroll
  for (int i = 0; i < 4; ++i)
    #pragma unroll
    for (int jj = 0; jj < 8; ++jj) acc[i][jj] = (floatx4){0.f, 0.f, 0.f, 0.f};

  for (int kk = 0; kk < 768; kk += 64) {
    const int jsh = kk >> 8, kc = kk & 255;
    __syncthreads();
    STAGE_A(comb + (((size_t)b * 4096 + ((l0 + row + jsh - 1 + 4096) & 4095)) << 8) + kc + cg)
    STAGE_B(W1 + (size_t)row * 768 + kk + cg)
    __syncthreads();
    #pragma unroll
    for (int ks = 0; ks < 64; ks += 32) {
      short8 af[4];
      #pragma unroll
      for (int i = 0; i < 4; ++i) {
        int row = i * 16 + r16;
        af[i] = *(const short8*)&lA[row * 64 + ((((ks >> 3) + quad) ^ (row & 7)) << 3)];
      }
      #pragma unroll
      for (int jj = 0; jj < 8; ++jj) {
        int row = wn + jj * 16 + r16;
        short8 bf = *(const short8*)&lB[row * 64 + ((((ks >> 3) + quad) ^ (row & 7)) << 3)];
        #pragma unroll
        for (int i = 0; i < 4; ++i)
          acc[i][jj] = __builtin_amdgcn_mfma_f32_16x16x32_bf16(bf, af[i], acc[i][jj], 0, 0, 0);
      }
    }
  }
  __syncthreads();
  // transpose to lT with conv bias added (pre-LN); bias read from global (L2)
  #pragma unroll
  for (int jj = 0; jj < 8; ++jj) {
    int n = wn + jj * 16 + quad * 4;
    float4 b4 = *(const float4*)&conv_b[n];
    #pragma unroll
    for (int i = 0; i < 4; ++i) {
      ushort4 pk;
      pk.x = f2b(acc[i][jj][0] + b4.x);
      pk.y = f2b(acc[i][jj][1] + b4.y);
      pk.z = f2b(acc[i][jj][2] + b4.z);
      pk.w = f2b(acc[i][jj][3] + b4.w);
      *(ushort4*)(lT + (size_t)(i * 16 + r16) * 520 + n) = pk;
    }
  }
  __syncthreads();
  // conv LN: write normalized ce to global (re-staged L2-hot in phase 2)
  {
    const int orow = tid >> 2, part = tid & 3;
    u16* rowp = lT + (size_t)orow * 520;
    float s1 = 0.f, s2 = 0.f;
    #pragma unroll
    for (int k = 0; k < 16; ++k) {
      short8 t8 = *(const short8*)(rowp + (part + k * 4) * 8);
      #pragma unroll
      for (int e = 0; e < 8; ++e) {
        float f = b2f((u16)t8[e]); s1 += f; s2 += f * f;
      }
    }
    s1 += __shfl_xor(s1, 1); s2 += __shfl_xor(s2, 1);
    s1 += __shfl_xor(s1, 2); s2 += __shfl_xor(s2, 2);
    float mean = s1 * (1.f / 512.f);
    float inv = rsqrtf(fmaxf(s2 * (1.f / 512.f) - mean * mean, 0.f) + 1e-5f);
    size_t mrow = (size_t)(m0 + orow) * 512;
    #pragma unroll
    for (int k = 0; k < 16; ++k) {
      int c8 = part + k * 4;
      short8 t8 = *(const short8*)(rowp + c8 * 8);
      short8 o;
      #pragma unroll
      for (int e = 0; e < 8; ++e) {
        int d = c8 * 8 + e;
        o[e] = (short)f2b(sG[d] * ((b2f((u16)t8[e]) - mean) * inv) + sB[d]);
      }
      *(short8*)(ce + mrow + c8 * 8) = o;
    }
  }
  __syncthreads();
  // reload gamma/beta with the tAPE LN params (epilogue use)
  if (tid < 128) {
    ((float4*)sG)[tid] = ((const float4*)g_t)[tid];
    ((float4*)sB)[tid] = ((const float4*)b_t)[tid];
  }

  // ===== phase 2: pre GEMM — proven staged structure, A = ce (L2-hot) =====
  floatx4 acc2[4][8];
  #pragma unroll
  for (int i = 0; i < 4; ++i)
    #pragma unroll
    for (int jj = 0; jj < 8; ++jj) acc2[i][jj] = (floatx4){0.f, 0.f, 0.f, 0.f};

  for (int kk = 0; kk < 512; kk += 64) {
    __syncthreads();   // first iter: also guarantees ce stores drained (vmcnt0)
    STAGE_A(ce + (size_t)(m0 + row) * 512 + kk + cg)
    STAGE_B(Wf + (size_t)row * 512 + kk + cg)
    __syncthreads();
    #pragma unroll
    for (int ks = 0; ks < 64; ks += 32) {
      short8 af[4];
      #pragma unroll
      for (int i = 0; i < 4; ++i) {
        int row = i * 16 + r16;
        af[i] = *(const short8*)&lA[row * 64 + ((((ks >> 3) + quad) ^ (row & 7)) << 3)];
      }
      #pragma unroll
      for (int jj = 0; jj < 8; ++jj) {
        int row = wn + jj * 16 + r16;
        short8 bf = *(const short8*)&lB[row * 64 + ((((ks >> 3) + quad) ^ (row & 7)) << 3)];
        #pragma unroll
        for (int i = 0; i < 4; ++i)
          acc2[i][jj] = __builtin_amdgcn_mfma_f32_16x16x32_bf16(bf, af[i], acc2[i][jj], 0, 0, 0);
      }
    }
  }
  __syncthreads();
  // transpose pre -> lT
  #pragma unroll
  for (int jj = 0; jj < 8; ++jj) {
    int n = wn + jj * 16 + quad * 4;
    #pragma unroll
    for (int i = 0; i < 4; ++i) {
      ushort4 pk;
      pk.x = f2b(acc2[i][jj][0]);
      pk.y = f2b(acc2[i][jj][1]);
      pk.z = f2b(acc2[i][jj][2]);
      pk.w = f2b(acc2[i][jj][3]);
      *(ushort4*)(lT + (size_t)(i * 16 + r16) * 520 + n) = pk;
    }
  }
  __syncthreads();
  // =============== epilogue: LN(pre+ctab) + weighted sum -> out ============
  const int orow = tid >> 2, part = tid & 3;
  const int m = m0 + orow, l = l0 + orow;
  const u16* rowp = lT + (size_t)orow * 520;
  const size_t lrow = (size_t)l * 512, mrow = (size_t)m * 512;
  float s1 = 0.f, s2 = 0.f;
  #pragma unroll
  for (int k = 0; k < 16; ++k) {
    int c8 = part + k * 4;
    short8 t8 = *(const short8*)(rowp + c8 * 8);
    short8 ct = *(const short8*)(ctab_bf + lrow + c8 * 8);
    #pragma unroll
    for (int e = 0; e < 8; ++e) {
      float f = b2f((u16)t8[e]) + b2f((u16)ct[e]);
      s1 += f; s2 += f * f;
    }
  }
  s1 += __shfl_xor(s1, 1); s2 += __shfl_xor(s2, 1);
  s1 += __shfl_xor(s1, 2); s2 += __shfl_xor(s2, 2);
  float mean = s1 * (1.f / 512.f);
  float inv = rsqrtf(fmaxf(s2 * (1.f / 512.f) - mean * mean, 0.f) + 1e-5f);

  float a0 = wp[0], a1 = wp[1], a2 = wp[2], a3 = wp[3];
  float mxw = fmaxf(fmaxf(a0, a1), fmaxf(a2, a3));
  float e0 = expf(a0 - mxw), e1 = expf(a1 - mxw), e2 = expf(a2 - mxw), e3 = expf(a3 - mxw);
  float invs = 1.f / (e0 + e1 + e2 + e3);
  float w0 = e0 * invs, w3 = e3 * invs;

  #pragma unroll
  for (int k = 0; k < 16; ++k) {
    int c8 = part + k * 4;
    short8 t8  = *(const short8*)(rowp + c8 * 8);
    short8 ct  = *(const short8*)(ctab_bf + lrow + c8 * 8);
    short8 c8v = *(const short8*)(ce + mrow + c8 * 8);
    short8 pw  = *(const short8*)(pw_tab + lrow + c8 * 8);
    float o[8];
    #pragma unroll
    for (int e = 0; e < 8; ++e) {
      int d = c8 * 8 + e;
      float f = b2f((u16)t8[e]) + b2f((u16)ct[e]);
      float pt = sG[d] * ((f - mean) * inv) + sB[d];
      o[e] = w0 * b2f((u16)c8v[e]) + b2f((u16)pw[e]) + w3 * pt;
    }
    float4* op = (float4*)(out + mrow + c8 * 8);
    op[0] = make_float4(o[0], o[1], o[2], o[3]);
    op[1] = make_float4(o[4], o[5], o[6], o[7]);
  }
}

// ---------------------------------------------------------------------------
extern "C" void kernel_launch(void* const* d_in, const int* in_sizes, int n_in,
                              void* d_out, int out_size, void* d_ws, size_t ws_size,
                              hipStream_t stream) {
  const float* x          = (const float*)d_in[0];
  const float* conv_w     = (const float*)d_in[1];
  const float* conv_b     = (const float*)d_in[2];
  const float* learned_pe = (const float*)d_in[3];
  const float* tape_pos   = (const float*)d_in[4];
  const float* tproj_w    = (const float*)d_in[5];
  const float* tproj_b    = (const float*)d_in[6];
  const float* mixer_w    = (const float*)d_in[7];
  const float* mixer_b    = (const float*)d_in[8];
  const float* g_c        = (const float*)d_in[9];
  const float* b_c        = (const float*)d_in[10];
  const float* g_f        = (const float*)d_in[11];
  const float* b_f        = (const float*)d_in[12];
  const float* g_l        = (const float*)d_in[13];
  const float* b_l        = (const float*)d_in[14];
  const float* g_t        = (const float*)d_in[15];
  const float* b_t        = (const float*)d_in[16];
  const float* wp         = (const float*)d_in[17];

  char* ws = (char*)d_ws;
  u16*  comb    = (u16*)(ws + 0);             // 32 MiB
  u16*  ce      = (u16*)(ws + 33554432);      // 64 MiB
  char* S       = ws + 100663296;
  u16*  W1      = (u16*)(S + 0);              // 768 KiB
  u16*  A_m1    = (u16*)(S + 786432);         // 512 KiB
  u16*  M2t     = (u16*)(S + 1310720);        // 512 KiB
  u16*  tprojT  = (u16*)(S + 1835008);        // 512 KiB
  u16*  tape_bf = (u16*)(S + 2359296);        // 4 MiB
  u16*  Wf      = (u16*)(S + 6553600);        // 512 KiB
  u16*  ctab_bf = (u16*)(S + 7077888);        // 4 MiB
  float* bias2  = (float*)(S + 11272192);     // 2 KiB
  u16*  pw_tab  = (u16*)(S + 11274240);       // 4 MiB

  // 1) all precompute + features in one launch (pe -> combined pw_tab)
  prep_all<<<14850, 256, 0, stream>>>(x, conv_w, mixer_w, tproj_w, tape_pos,
                                      tproj_b, mixer_b, learned_pe,
                                      g_f, b_f, g_l, b_l, wp,
                                      W1, A_m1, M2t, tprojT, tape_bf,
                                      bias2, pw_tab, comb);
  // 2) both small GEMMs (Wf, ctab) in one launch
  gemm_bt_both<<<144, 256, 0, stream>>>(A_m1, tprojT, Wf, tape_bf, M2t,
                                        ctab_bf, bias2);
  // 3) fused conv GEMM + LN + pre GEMM + LN + weighted sum
  gemm_conv_pre<<<1024, 256, 0, stream>>>(comb, W1, conv_b, g_c, b_c,
                                          Wf, ctab_bf, pw_tab,
                                          g_t, b_t, wp, ce, (float*)d_out);
}